// Round 16
// baseline (372.505 us; speedup 1.0000x reference)
//
#include <hip/hip_runtime.h>

typedef unsigned short u16;
typedef unsigned int u32;
typedef short bf16x8 __attribute__((ext_vector_type(8)));
typedef float f32x16 __attribute__((ext_vector_type(16)));
typedef u16 u16x8 __attribute__((ext_vector_type(8)));

#define DIM 96
#define PLANE (DIM*DIM)   // 9216
#define S 884736          // 96^3
#define C 64
#define HALF 32
#define PARTS 16
#define EPS 1e-5f

// bf16 LDS rows of 104 u16: data cols 0..95 at +8, zero pad chunks at 104*k
#define RPAD 104
#define LROWS 18
#define LBUF (8 + LROWS*RPAD)     // dwconv buffer (18 rows)
#define FDCH 12                   // fused_lo d-chunk (DIM/FDCH = 8 grid-y)

#define MFMA32(a,b,c) __builtin_amdgcn_mfma_f32_32x32x16_bf16(a,b,c,0,0,0)

__device__ __forceinline__ u16 f2bf(float f) {          // RNE, finite inputs
  u32 u = __builtin_bit_cast(u32, f);
  return (u16)((u + 0x7FFFu + ((u >> 16) & 1u)) >> 16);
}
__device__ __forceinline__ float bf2f(u16 h) {
  return __builtin_bit_cast(float, (u32)h << 16);
}
__device__ __forceinline__ u32 cvt_pk_bf16(float lo, float hi) {  // lo->[15:0], hi->[31:16]
  u32 r;
  asm("v_cvt_pk_bf16_f32 %0, %1, %2" : "=v"(r) : "v"(lo), "v"(hi));
  return r;
}
__device__ __forceinline__ float silu(float v) { return v / (1.f + __expf(-v)); }
__device__ __forceinline__ u16x8 zero8() {
  u16x8 z;
  #pragma unroll
  for (int i = 0; i < 8; ++i) z[i] = 0;
  return z;
}

// ---- K1: per-channel partial sums (deterministic) + bf16 copy of x -----------
__global__ __launch_bounds__(256) void k1_stats(const float* __restrict__ x,
                                                u16* __restrict__ xb,
                                                float* __restrict__ psum,
                                                float* __restrict__ psq) {
  const int bid = blockIdx.x;              // 0 .. C*PARTS-1
  const int ch = bid / PARTS, part = bid % PARTS;
  const int chunk = S / PARTS;
  const size_t base = (size_t)ch * S + (size_t)part * chunk;
  const float4* p = (const float4*)(x + base);
  ushort4* xb4 = (ushort4*)(xb + base);
  const int n4 = chunk / 4;
  float s = 0.f, q = 0.f;
  for (int i = threadIdx.x; i < n4; i += 256) {
    float4 v = p[i];
    s += (v.x + v.y) + (v.z + v.w);
    q += (v.x * v.x + v.y * v.y) + (v.z * v.z + v.w * v.w);
    union { u32 u[2]; ushort4 v4; } o;
    o.u[0] = cvt_pk_bf16(v.x, v.y);
    o.u[1] = cvt_pk_bf16(v.z, v.w);
    xb4[i] = o.v4;
  }
  #pragma unroll
  for (int off = 32; off > 0; off >>= 1) {
    s += __shfl_down(s, off);
    q += __shfl_down(q, off);
  }
  __shared__ float ls[4], lq[4];
  const int wid = threadIdx.x >> 6, lane = threadIdx.x & 63;
  if (lane == 0) { ls[wid] = s; lq[wid] = q; }
  __syncthreads();
  if (threadIdx.x == 0) {
    psum[bid] = (ls[0] + ls[1]) + (ls[2] + ls[3]);
    psq[bid]  = (lq[0] + lq[1]) + (lq[2] + lq[3]);
  }
}

// ------ K1b: finalize stats; emit bf16 folded in_proj W, bf16 out_proj W ------
__global__ __launch_bounds__(64) void k1b_prep(const float* __restrict__ psum,
    const float* __restrict__ psq,
    const float* __restrict__ norm_w, const float* __restrict__ norm_b,
    const float* __restrict__ in_w, const float* __restrict__ in_b,
    const float* __restrict__ out_w,
    u16* __restrict__ Wp, float* __restrict__ biasp, u16* __restrict__ Wo) {
  __shared__ float a_s[C], b2_s[C];
  const int t = threadIdx.x;               // 0..63 (output row o)
  float s = 0.f, q = 0.f;
  for (int i = 0; i < PARTS; ++i) { s += psum[t * PARTS + i]; q += psq[t * PARTS + i]; }
  const float inv = 1.f / (float)S;
  const float mu = s * inv;
  const float var = q * inv - mu * mu;
  const float rsig = rsqrtf(var + EPS);
  const float a = norm_w[t] * rsig;
  const float b2 = norm_b[t] - mu * a;
  a_s[t] = a; b2_s[t] = b2;
  __syncthreads();
  float bp = in_b[t];
  for (int c = 0; c < C; ++c) {
    const float w = in_w[t * C + c];
    Wp[t * C + c] = f2bf(w * a_s[c]);      // folded norm scale, row-major [o][c]
    bp += b2_s[c] * w;                     // folded norm shift
    Wo[t * C + c] = f2bf(out_w[t * C + c]);
  }
  biasp[t] = bp;
}

// ------ K2: 1x1 in_proj, 32x32x16 MFMA, even/odd interleaved voxel tiles ------
__global__ __launch_bounds__(256) void k2_mfma(const u16* __restrict__ xb,
    const u16* __restrict__ Wp, const float* __restrict__ biasp,
    u16* __restrict__ xp) {
  const int lane = threadIdx.x & 63, wid = threadIdx.x >> 6;
  const int n = lane & 31, hf = lane >> 5;
  const int v0 = blockIdx.x * 256 + wid * 64;      // 64 voxels per wave
  bf16x8 A[2][4];                                  // [o-tile][k-slice]
  #pragma unroll
  for (int t = 0; t < 2; ++t)
    #pragma unroll
    for (int s = 0; s < 4; ++s)
      A[t][s] = *(const bf16x8*)(Wp + (t * 32 + n) * C + s * 16 + hf * 8);

  f32x16 accE[2], accO[2];
  #pragma unroll
  for (int t = 0; t < 2; ++t)
    #pragma unroll
    for (int r = 0; r < 16; ++r) {
      const float b = biasp[t * 32 + (r & 3) + 8 * (r >> 2) + 4 * hf];
      accE[t][r] = b; accO[t][r] = b;
    }

  #pragma unroll
  for (int s = 0; s < 4; ++s) {
    union { u16 u[8]; bf16x8 v; } BE, BO;
    #pragma unroll
    for (int j = 0; j < 8; ++j) {
      const u32 xv = *(const u32*)(xb + (size_t)(s * 16 + hf * 8 + j) * S + v0 + 2 * n);
      BE.u[j] = (u16)(xv & 0xFFFFu); BO.u[j] = (u16)(xv >> 16);
    }
    #pragma unroll
    for (int t = 0; t < 2; ++t) {
      accE[t] = MFMA32(A[t][s], BE.v, accE[t]);
      accO[t] = MFMA32(A[t][s], BO.v, accO[t]);
    }
  }
  #pragma unroll
  for (int t = 0; t < 2; ++t)
    #pragma unroll
    for (int r = 0; r < 16; ++r) {
      const int o = t * 32 + (r & 3) + 8 * (r >> 2) + 4 * hf;
      *(u32*)(xp + (size_t)o * S + v0 + 2 * n) = cvt_pk_bf16(accE[t][r], accO[t][r]);
    }
}

// ---------------- helpers shared by conv kernels ------------------------------
__device__ __forceinline__ void fma3(float* __restrict__ a,
    const float* __restrict__ r, float t0, float t1, float t2) {
  #pragma unroll
  for (int i = 0; i < 8; ++i) a[i] = fmaf(t0, r[i], a[i]);
  #pragma unroll
  for (int i = 0; i < 8; ++i) a[i] = fmaf(t1, r[i + 1], a[i]);
  #pragma unroll
  for (int i = 0; i < 8; ++i) a[i] = fmaf(t2, r[i + 2], a[i]);
}

// ---- dwconv (sym half): LDS-staged planes, A/B tap-carry, dbuf ---------------
template<bool SILU, int DCHUNKT>
__global__ __launch_bounds__(192) void dwconv(const u16* __restrict__ srcA,
    const float* __restrict__ kwA, const float* __restrict__ bA,
    u16* __restrict__ dstA) {
  __shared__ u16 lds[2][LBUF];
  const int c = blockIdx.z;
  const u16* src = srcA + (size_t)c * S;
  u16* dst = dstA + (size_t)c * S;
  const float* kwp = kwA + c * 27;
  float kw[27];                            // wave-uniform
  #pragma unroll
  for (int i = 0; i < 27; ++i) kw[i] = kwp[i];
  const float bias = bA[c];

  const int tx = threadIdx.x, ty = threadIdx.y;    // 12 x 16
  const int tid = ty * 12 + tx;
  const int w8 = tx * 8;
  const int h0 = blockIdx.x * 16;
  const int d0 = blockIdx.y * DCHUNKT;

  if (tid < 38) {
    const int b = tid / 19, k = tid % 19;
    *(u16x8*)&lds[b][RPAD * k] = zero8();
  }

  const int s_row0 = tid / 12, s_cc0 = tid % 12;
  const int s_row1 = (192 + tid) / 12, s_cc1 = (192 + tid) % 12;
  const bool has2 = tid < 24;
  const int s_h0 = h0 - 1 + s_row0;
  const int s_h1 = h0 - 1 + s_row1;
  const bool h0ok = (unsigned)s_h0 < DIM;
  const bool h1ok = has2 && ((unsigned)s_h1 < DIM);
  u16x8 vs0, vs1;

  #define STAGE_LOAD(DD) { \
    vs0 = zero8(); vs1 = zero8(); \
    if (((unsigned)(DD) < DIM) && h0ok) \
      vs0 = *(const u16x8*)(src + (size_t)(DD) * PLANE + s_h0 * DIM + s_cc0 * 8); \
    if (((unsigned)(DD) < DIM) && h1ok) \
      vs1 = *(const u16x8*)(src + (size_t)(DD) * PLANE + s_h1 * DIM + s_cc1 * 8); }

  #define STAGE_WRITE(WB) { \
    *(u16x8*)&lds[WB][8 + s_row0 * RPAD + s_cc0 * 8] = vs0; \
    if (has2) *(u16x8*)&lds[WB][8 + s_row1 * RPAD + s_cc1 * 8] = vs1; }

  float r0[10], r1[10], r2[10];
  float A[8], B[8], o8[8];

  #define LOADROW(R, ROWI, RB) { \
    const u16* _lb = &lds[RB][8 + (ROWI) * RPAD + w8]; \
    const u16x8 _m = *(const u16x8*)_lb; \
    const u16 _lo = _lb[-1], _hi = _lb[8]; \
    R[0] = bf2f(_lo); \
    _Pragma("unroll") \
    for (int i = 0; i < 8; ++i) R[1 + i] = bf2f(_m[i]); \
    R[9] = bf2f(_hi); }

  #define LOADROWS(RB) { LOADROW(r0, ty, RB); LOADROW(r1, ty + 1, RB); LOADROW(r2, ty + 2, RB); }

  #define CBLK(ACC, K0) { \
    fma3(ACC, r0, kw[(K0) + 0], kw[(K0) + 1], kw[(K0) + 2]); \
    fma3(ACC, r1, kw[(K0) + 3], kw[(K0) + 4], kw[(K0) + 5]); \
    fma3(ACC, r2, kw[(K0) + 6], kw[(K0) + 7], kw[(K0) + 8]); }

  STAGE_LOAD(d0 - 1);
  STAGE_WRITE(0);
  __syncthreads();

  LOADROWS(0);
  STAGE_LOAD(d0);
  #pragma unroll
  for (int i = 0; i < 8; ++i) B[i] = bias;
  CBLK(B, 0);
  STAGE_WRITE(1);
  __syncthreads();

  LOADROWS(1);
  STAGE_LOAD(d0 + 1);
  #pragma unroll
  for (int i = 0; i < 8; ++i) { A[i] = B[i]; B[i] = bias; }
  CBLK(A, 9);
  CBLK(B, 0);
  STAGE_WRITE(0);
  __syncthreads();

  u16* db = dst + (size_t)d0 * PLANE + (size_t)(h0 + ty) * DIM + w8;

  #define ROUND_BODY(D, RB, WB, DO_STG) { \
    LOADROWS(RB); \
    if (DO_STG) STAGE_LOAD((D) + 2); \
    _Pragma("unroll") \
    for (int i = 0; i < 8; ++i) o8[i] = A[i]; \
    CBLK(o8, 18); \
    _Pragma("unroll") \
    for (int i = 0; i < 8; ++i) A[i] = B[i]; \
    CBLK(A, 9); \
    _Pragma("unroll") \
    for (int i = 0; i < 8; ++i) B[i] = bias; \
    CBLK(B, 0); \
    if (SILU) { \
      _Pragma("unroll") \
      for (int i = 0; i < 8; ++i) o8[i] = silu(o8[i]); \
    } \
    union { u32 u[4]; u16x8 v; } _o; \
    _Pragma("unroll") \
    for (int i = 0; i < 4; ++i) _o.u[i] = cvt_pk_bf16(o8[2 * i], o8[2 * i + 1]); \
    *(u16x8*)db = _o.v; \
    db += PLANE; \
    if (DO_STG) STAGE_WRITE(WB); \
    __syncthreads(); }

  #pragma unroll 1
  for (int d = d0; d < d0 + DCHUNKT; d += 2) {
    ROUND_BODY(d, 0, 1, true);
    ROUND_BODY(d + 1, 1, 0, (d + 2) < d0 + DCHUNKT);
  }
  #undef ROUND_BODY
  #undef CBLK
  #undef LOADROWS
  #undef LOADROW
  #undef STAGE_WRITE
  #undef STAGE_LOAD
}

// ---- fused_lo: ssm conv + SiLU -> LDS t1 ring -> mamba conv, channels 0..31 --
// Blocks: (12,18) threads. Per step: consume IN plane j (t1 carries, emit
// t1(j-1) to LDS), one barrier, consume t1 plane j-1 (z carries, emit z(j-2)).
__global__ __launch_bounds__(216) void fused_lo(const u16* __restrict__ xp,
    const float* __restrict__ ssm_w, const float* __restrict__ ssm_b,
    const float* __restrict__ mam_w, const float* __restrict__ mam_b,
    u16* __restrict__ z_lo) {
  __shared__ u16 inb[2][8 + 20 * RPAD];    // input tile: 20 rows (h-halo 2)
  __shared__ u16 tb[2][8 + 18 * RPAD];     // t1 tile: 18 rows (h-halo 1)
  const int c = blockIdx.z;
  const u16* src = xp + (size_t)c * S;
  u16* zdst = z_lo + (size_t)c * S;
  float kw1[27], kw2[27];
  #pragma unroll
  for (int i = 0; i < 27; ++i) { kw1[i] = ssm_w[c * 27 + i]; kw2[i] = mam_w[c * 27 + i]; }
  const float bias1 = ssm_b[c], bias2 = mam_b[c];

  const int tx = threadIdx.x, ty = threadIdx.y;    // 12 x 18
  const int tid = ty * 12 + tx;
  const int w8 = tx * 8;
  const int h0 = blockIdx.x * 16;
  const int d0 = blockIdx.y * FDCH;

  // zero pad chunks once (inb: 21/buf, tb: 19/buf)
  if (tid < 42) { *(u16x8*)&inb[tid / 21][(tid % 21) * RPAD] = zero8(); }
  else if (tid < 80) { const int t2 = tid - 42; *(u16x8*)&tb[t2 / 19][(t2 % 19) * RPAD] = zero8(); }

  // staging: 240 chunks = 20 rows x 12; c0 = tid, c1 = 216+tid (tid<24)
  const int s_row0 = ty, s_cc0 = tx;               // rows 0..17
  const int s_row1 = 18 + tid / 12, s_cc1 = tid % 12;
  const bool has2 = tid < 24;
  const int gh0 = h0 - 2 + s_row0;
  const int gh1 = h0 - 2 + s_row1;
  const bool g0ok = (unsigned)gh0 < DIM;
  const bool g1ok = has2 && ((unsigned)gh1 < DIM);
  u16x8 vs0, vs1;

  #define FS_LOAD(DD) { \
    vs0 = zero8(); vs1 = zero8(); \
    if (((unsigned)(DD) < DIM) && g0ok) \
      vs0 = *(const u16x8*)(src + (size_t)(DD) * PLANE + gh0 * DIM + s_cc0 * 8); \
    if (((unsigned)(DD) < DIM) && g1ok) \
      vs1 = *(const u16x8*)(src + (size_t)(DD) * PLANE + gh1 * DIM + s_cc1 * 8); }

  #define FS_WRITE(WB) { \
    *(u16x8*)&inb[WB][8 + s_row0 * RPAD + s_cc0 * 8] = vs0; \
    if (has2) *(u16x8*)&inb[WB][8 + s_row1 * RPAD + s_cc1 * 8] = vs1; }

  const bool t1_h_ok = (unsigned)(h0 - 1 + ty) < DIM;  // t1 row validity
  const bool zrole = ty < 16;
  u16* zrow = zdst + (size_t)(h0 + ty) * DIM + w8;

  float r0[10], r1[10], r2[10];
  float A1[8], B1[8], A2[8], B2[8], o8[8];

  #define FLOADROW(R, ROWI, BASE) { \
    const u16* _lb = (BASE) + 8 + (ROWI) * RPAD + w8; \
    const u16x8 _m = *(const u16x8*)_lb; \
    const u16 _lo = _lb[-1], _hi = _lb[8]; \
    R[0] = bf2f(_lo); \
    _Pragma("unroll") \
    for (int i = 0; i < 8; ++i) R[1 + i] = bf2f(_m[i]); \
    R[9] = bf2f(_hi); }

  #define FROWS(BASE) { FLOADROW(r0, ty, BASE); FLOADROW(r1, ty + 1, BASE); FLOADROW(r2, ty + 2, BASE); }

  #define CBLKW(ACC, KW, K0) { \
    fma3(ACC, r0, KW[(K0) + 0], KW[(K0) + 1], KW[(K0) + 2]); \
    fma3(ACC, r1, KW[(K0) + 3], KW[(K0) + 4], KW[(K0) + 5]); \
    fma3(ACC, r2, KW[(K0) + 6], KW[(K0) + 7], KW[(K0) + 8]); }

  // t1 emission: plane tt = j-1; write SiLU(o8) or zeros to tb[TT] row ty
  #define TEMIT(TT, TVAL) { \
    union { u32 u[4]; u16x8 v; } _t; \
    if (TVAL) { \
      _Pragma("unroll") \
      for (int i = 0; i < 8; ++i) o8[i] = silu(o8[i]); \
      _Pragma("unroll") \
      for (int i = 0; i < 4; ++i) _t.u[i] = cvt_pk_bf16(o8[2 * i], o8[2 * i + 1]); \
    } else _t.v = zero8(); \
    *(u16x8*)&tb[TT][8 + ty * RPAD + w8] = _t.v; }

  // ---- prologue: stage IN(d0-2) into buf0 ----
  FS_LOAD(d0 - 2);
  FS_WRITE(0);
  __syncthreads();

  // k=0: consume IN(d0-2) [buf0]; B1 = bias1 + C0
  FS_LOAD(d0 - 1);
  FROWS(inb[0]);
  #pragma unroll
  for (int i = 0; i < 8; ++i) B1[i] = bias1;
  CBLKW(B1, kw1, 0);
  FS_WRITE(1);
  __syncthreads();

  // k=1: consume IN(d0-1) [buf1]; A1 = B1 + C1; B1 = bias1 + C0
  FS_LOAD(d0);
  FROWS(inb[1]);
  #pragma unroll
  for (int i = 0; i < 8; ++i) { A1[i] = B1[i]; B1[i] = bias1; }
  CBLKW(A1, kw1, 9);
  CBLKW(B1, kw1, 0);
  FS_WRITE(0);
  __syncthreads();

  // k=2: consume IN(d0) [buf0]; emit t1(d0-1) -> tb[1]; z: B2 prime
  FS_LOAD(d0 + 1);
  FROWS(inb[0]);
  #pragma unroll
  for (int i = 0; i < 8; ++i) o8[i] = A1[i];
  CBLKW(o8, kw1, 18);
  #pragma unroll
  for (int i = 0; i < 8; ++i) { A1[i] = B1[i]; B1[i] = bias1; }
  CBLKW(A1, kw1, 9);
  CBLKW(B1, kw1, 0);
  { const bool tval = ((unsigned)(d0 - 1) < DIM) && t1_h_ok; TEMIT(1, tval); }
  FS_WRITE(1);
  __syncthreads();
  if (zrole) {
    FROWS(tb[1]);
    #pragma unroll
    for (int i = 0; i < 8; ++i) B2[i] = bias2;
    CBLKW(B2, kw2, 0);
  }

  // k=3: consume IN(d0+1) [buf1]; emit t1(d0) -> tb[0]; z: A2,B2 prime
  FS_LOAD(d0 + 2);
  FROWS(inb[1]);
  #pragma unroll
  for (int i = 0; i < 8; ++i) o8[i] = A1[i];
  CBLKW(o8, kw1, 18);
  #pragma unroll
  for (int i = 0; i < 8; ++i) { A1[i] = B1[i]; B1[i] = bias1; }
  CBLKW(A1, kw1, 9);
  CBLKW(B1, kw1, 0);
  TEMIT(0, t1_h_ok);                       // plane d0 always < DIM
  FS_WRITE(0);
  __syncthreads();
  if (zrole) {
    FROWS(tb[0]);
    #pragma unroll
    for (int i = 0; i < 8; ++i) { A2[i] = B2[i]; B2[i] = bias2; }
    CBLKW(A2, kw2, 9);
    CBLKW(B2, kw2, 0);
  }

  // ---- main: k = 4 .. FDCH+3; IB = k&1, TT = (k+1)&1 ----
  #define FSTEP(K, IB, TT) { \
    const int jj = d0 - 2 + (K); \
    if ((K) < FDCH + 3) FS_LOAD(jj + 1); \
    FROWS(inb[IB]); \
    _Pragma("unroll") \
    for (int i = 0; i < 8; ++i) o8[i] = A1[i]; \
    CBLKW(o8, kw1, 18); \
    _Pragma("unroll") \
    for (int i = 0; i < 8; ++i) { A1[i] = B1[i]; B1[i] = bias1; } \
    CBLKW(A1, kw1, 9); \
    CBLKW(B1, kw1, 0); \
    { const bool tval = ((unsigned)(jj - 1) < DIM) && t1_h_ok; TEMIT(TT, tval); } \
    if ((K) < FDCH + 3) FS_WRITE(IB ^ 1); \
    __syncthreads(); \
    if (zrole) { \
      FROWS(tb[TT]); \
      _Pragma("unroll") \
      for (int i = 0; i < 8; ++i) o8[i] = A2[i]; \
      CBLKW(o8, kw2, 18); \
      _Pragma("unroll") \
      for (int i = 0; i < 8; ++i) { A2[i] = B2[i]; B2[i] = bias2; } \
      CBLKW(A2, kw2, 9); \
      CBLKW(B2, kw2, 0); \
      union { u32 u[4]; u16x8 v; } _z; \
      _Pragma("unroll") \
      for (int i = 0; i < 4; ++i) _z.u[i] = cvt_pk_bf16(o8[2 * i], o8[2 * i + 1]); \
      *(u16x8*)(zrow + (size_t)(jj - 2) * PLANE) = _z.v; \
    } }

  #pragma unroll 1
  for (int k = 4; k < FDCH + 4; k += 2) {
    FSTEP(k, 0, 1);
    FSTEP(k + 1, 1, 0);
  }
  #undef FSTEP
  #undef TEMIT
  #undef CBLKW
  #undef FROWS
  #undef FLOADROW
  #undef FS_WRITE
  #undef FS_LOAD
}

// --- K4b: 1x1 out_proj (32x32x16 MFMA) + bias + bf16 residual -> fp32 out -----
__global__ __launch_bounds__(256) void k4b_mfma(const u16* __restrict__ z_lo,
    const u16* __restrict__ z_hi, const u16* __restrict__ xb,
    const u16* __restrict__ Wo, const float* __restrict__ ob,
    float* __restrict__ out) {
  const int lane = threadIdx.x & 63, wid = threadIdx.x >> 6;
  const int n = lane & 31, hf = lane >> 5;
  const int v0 = blockIdx.x * 256 + wid * 64;
  bf16x8 A[2][4];
  #pragma unroll
  for (int t = 0; t < 2; ++t)
    #pragma unroll
    for (int s = 0; s < 4; ++s)
      A[t][s] = *(const bf16x8*)(Wo + (t * 32 + n) * C + s * 16 + hf * 8);

  f32x16 accE[2], accO[2];
  #pragma unroll
  for (int t = 0; t < 2; ++t)
    #pragma unroll
    for (int r = 0; r < 16; ++r) {
      const float b = ob[t * 32 + (r & 3) + 8 * (r >> 2) + 4 * hf];
      accE[t][r] = b; accO[t][r] = b;
    }

  #pragma unroll
  for (int s = 0; s < 4; ++s) {
    const u16* zbase = (s < 2) ? z_lo + (size_t)(s * 16) * S
                               : z_hi + (size_t)((s - 2) * 16) * S;
    union { u16 u[8]; bf16x8 v; } BE, BO;
    #pragma unroll
    for (int j = 0; j < 8; ++j) {
      const u32 zv = *(const u32*)(zbase + (size_t)(hf * 8 + j) * S + v0 + 2 * n);
      BE.u[j] = (u16)(zv & 0xFFFFu); BO.u[j] = (u16)(zv >> 16);
    }
    #pragma unroll
    for (int t = 0; t < 2; ++t) {
      accE[t] = MFMA32(A[t][s], BE.v, accE[t]);
      accO[t] = MFMA32(A[t][s], BO.v, accO[t]);
    }
  }
  #pragma unroll
  for (int t = 0; t < 2; ++t)
    #pragma unroll
    for (int r = 0; r < 16; ++r) {
      const int o = t * 32 + (r & 3) + 8 * (r >> 2) + 4 * hf;
      const u32 xr = *(const u32*)(xb + (size_t)o * S + v0 + 2 * n);
      float2 ov;
      ov.x = accE[t][r] + bf2f((u16)(xr & 0xFFFFu));
      ov.y = accO[t][r] + bf2f((u16)(xr >> 16));
      *(float2*)(out + (size_t)o * S + v0 + 2 * n) = ov;
    }
}

extern "C" void kernel_launch(void* const* d_in, const int* in_sizes, int n_in,
                              void* d_out, int out_size, void* d_ws, size_t ws_size,
                              hipStream_t stream) {
  const float* x      = (const float*)d_in[0];
  const float* norm_w = (const float*)d_in[1];
  const float* norm_b = (const float*)d_in[2];
  const float* in_w   = (const float*)d_in[3];
  const float* in_b   = (const float*)d_in[4];
  const float* ssm_w  = (const float*)d_in[5];
  const float* ssm_b  = (const float*)d_in[6];
  const float* mam_w  = (const float*)d_in[7];
  const float* mam_b  = (const float*)d_in[8];
  const float* sym_w  = (const float*)d_in[9];
  const float* sym_b  = (const float*)d_in[10];
  const float* out_w  = (const float*)d_in[11];
  const float* out_b  = (const float*)d_in[12];
  float* out = (float*)d_out;

  // Workspace (u16 units). t1 eliminated (lives in fused_lo's LDS); z_lo is a
  // real buffer (cross-block d-halo reads of xp forbid aliasing). ~340 MB.
  u16* xb   = (u16*)d_ws;                      // C*S bf16 copy of x (113.2 MB)
  u16* xp   = xb + (size_t)C * S;              // C*S bf16 (113.2 MB)
  u16* z_lo = xp + (size_t)C * S;              // HALF*S bf16 (56.6 MB)
  u16* z_hi = z_lo + (size_t)HALF * S;         // HALF*S bf16 (56.6 MB)
  float* psum  = (float*)(z_hi + (size_t)HALF * S);  // C*PARTS
  float* psq   = psum + C * PARTS;             // C*PARTS
  u16* Wp      = (u16*)(psq + C * PARTS);      // C*C bf16
  u16* Wo      = Wp + C * C;                   // C*C bf16
  float* biasp = (float*)(Wo + C * C);         // C fp32

  k1_stats<<<C * PARTS, 256, 0, stream>>>(x, xb, psum, psq);
  k1b_prep<<<1, 64, 0, stream>>>(psum, psq, norm_w, norm_b, in_w, in_b, out_w,
                                 Wp, biasp, Wo);
  k2_mfma<<<S / 256, 256, 0, stream>>>(xb, Wp, biasp, xp);
  // sym half: SiLU(conv_sym(xp[32:64])) -> z_hi
  dwconv<true, 12><<<dim3(DIM / 16, 8, HALF), dim3(12, 16, 1), 0, stream>>>(
      xp + (size_t)HALF * S, sym_w, sym_b, z_hi);
  // fused x1 pipeline: conv_mamba(SiLU(conv_ssm(xp[0:32]))) -> z_lo
  fused_lo<<<dim3(DIM / 16, DIM / FDCH, HALF), dim3(12, 18, 1), 0, stream>>>(
      xp, ssm_w, ssm_b, mam_w, mam_b, z_lo);
  k4b_mfma<<<S / 256, 256, 0, stream>>>(z_lo, z_hi, xb, Wo, out_b, out);
}

// Round 17
// 353.188 us; speedup vs baseline: 1.0547x; 1.0547x over previous
//
#include <hip/hip_runtime.h>

typedef unsigned short u16;
typedef unsigned int u32;
typedef short bf16x8 __attribute__((ext_vector_type(8)));
typedef float f32x16 __attribute__((ext_vector_type(16)));
typedef u16 u16x8 __attribute__((ext_vector_type(8)));

#define DIM 96
#define PLANE (DIM*DIM)   // 9216
#define S 884736          // 96^3
#define C 64
#define HALF 32
#define PARTS 16
#define EPS 1e-5f

// bf16 LDS tile: rows of 104 u16 (data cols 0..95 at +8, zero pads at 104*k..104*k+7)
#define RPAD 104
#define LROWS 18
#define LBUF (8 + LROWS*RPAD)   // 1880 u16 per buffer

#define MFMA32(a,b,c) __builtin_amdgcn_mfma_f32_32x32x16_bf16(a,b,c,0,0,0)

__device__ __forceinline__ u16 f2bf(float f) {          // RNE, finite inputs
  u32 u = __builtin_bit_cast(u32, f);
  return (u16)((u + 0x7FFFu + ((u >> 16) & 1u)) >> 16);
}
__device__ __forceinline__ float bf2f(u16 h) {
  return __builtin_bit_cast(float, (u32)h << 16);
}
__device__ __forceinline__ u32 cvt_pk_bf16(float lo, float hi) {  // lo->[15:0], hi->[31:16]
  u32 r;
  asm("v_cvt_pk_bf16_f32 %0, %1, %2" : "=v"(r) : "v"(lo), "v"(hi));
  return r;
}
__device__ __forceinline__ float silu(float v) { return v / (1.f + __expf(-v)); }
__device__ __forceinline__ u16x8 zero8() {
  u16x8 z;
  #pragma unroll
  for (int i = 0; i < 8; ++i) z[i] = 0;
  return z;
}

// ---- K1: per-channel partial sums (deterministic) + bf16 copy of x -----------
__global__ __launch_bounds__(256) void k1_stats(const float* __restrict__ x,
                                                u16* __restrict__ xb,
                                                float* __restrict__ psum,
                                                float* __restrict__ psq) {
  const int bid = blockIdx.x;              // 0 .. C*PARTS-1
  const int ch = bid / PARTS, part = bid % PARTS;
  const int chunk = S / PARTS;
  const size_t base = (size_t)ch * S + (size_t)part * chunk;
  const float4* p = (const float4*)(x + base);
  ushort4* xb4 = (ushort4*)(xb + base);
  const int n4 = chunk / 4;
  float s = 0.f, q = 0.f;
  for (int i = threadIdx.x; i < n4; i += 256) {
    float4 v = p[i];
    s += (v.x + v.y) + (v.z + v.w);
    q += (v.x * v.x + v.y * v.y) + (v.z * v.z + v.w * v.w);
    union { u32 u[2]; ushort4 v4; } o;
    o.u[0] = cvt_pk_bf16(v.x, v.y);
    o.u[1] = cvt_pk_bf16(v.z, v.w);
    xb4[i] = o.v4;
  }
  #pragma unroll
  for (int off = 32; off > 0; off >>= 1) {
    s += __shfl_down(s, off);
    q += __shfl_down(q, off);
  }
  __shared__ float ls[4], lq[4];
  const int wid = threadIdx.x >> 6, lane = threadIdx.x & 63;
  if (lane == 0) { ls[wid] = s; lq[wid] = q; }
  __syncthreads();
  if (threadIdx.x == 0) {
    psum[bid] = (ls[0] + ls[1]) + (ls[2] + ls[3]);
    psq[bid]  = (lq[0] + lq[1]) + (lq[2] + lq[3]);
  }
}

// ------ K1b: finalize stats; emit bf16 folded in_proj W, bf16 out_proj W ------
__global__ __launch_bounds__(64) void k1b_prep(const float* __restrict__ psum,
    const float* __restrict__ psq,
    const float* __restrict__ norm_w, const float* __restrict__ norm_b,
    const float* __restrict__ in_w, const float* __restrict__ in_b,
    const float* __restrict__ out_w,
    u16* __restrict__ Wp, float* __restrict__ biasp, u16* __restrict__ Wo) {
  __shared__ float a_s[C], b2_s[C];
  const int t = threadIdx.x;               // 0..63 (output row o)
  float s = 0.f, q = 0.f;
  for (int i = 0; i < PARTS; ++i) { s += psum[t * PARTS + i]; q += psq[t * PARTS + i]; }
  const float inv = 1.f / (float)S;
  const float mu = s * inv;
  const float var = q * inv - mu * mu;
  const float rsig = rsqrtf(var + EPS);
  const float a = norm_w[t] * rsig;
  const float b2 = norm_b[t] - mu * a;
  a_s[t] = a; b2_s[t] = b2;
  __syncthreads();
  float bp = in_b[t];
  for (int c = 0; c < C; ++c) {
    const float w = in_w[t * C + c];
    Wp[t * C + c] = f2bf(w * a_s[c]);      // folded norm scale, row-major [o][c]
    bp += b2_s[c] * w;                     // folded norm shift
    Wo[t * C + c] = f2bf(out_w[t * C + c]);
  }
  biasp[t] = bp;
}

// ------ K2: 1x1 in_proj, 32x32x16 MFMA, even/odd interleaved voxel tiles ------
__global__ __launch_bounds__(256) void k2_mfma(const u16* __restrict__ xb,
    const u16* __restrict__ Wp, const float* __restrict__ biasp,
    u16* __restrict__ xp) {
  const int lane = threadIdx.x & 63, wid = threadIdx.x >> 6;
  const int n = lane & 31, hf = lane >> 5;
  const int v0 = blockIdx.x * 256 + wid * 64;      // 64 voxels per wave
  bf16x8 A[2][4];                                  // [o-tile][k-slice]
  #pragma unroll
  for (int t = 0; t < 2; ++t)
    #pragma unroll
    for (int s = 0; s < 4; ++s)
      A[t][s] = *(const bf16x8*)(Wp + (t * 32 + n) * C + s * 16 + hf * 8);

  f32x16 accE[2], accO[2];
  #pragma unroll
  for (int t = 0; t < 2; ++t)
    #pragma unroll
    for (int r = 0; r < 16; ++r) {
      const float b = biasp[t * 32 + (r & 3) + 8 * (r >> 2) + 4 * hf];
      accE[t][r] = b; accO[t][r] = b;
    }

  #pragma unroll
  for (int s = 0; s < 4; ++s) {
    union { u16 u[8]; bf16x8 v; } BE, BO;
    #pragma unroll
    for (int j = 0; j < 8; ++j) {
      const u32 xv = *(const u32*)(xb + (size_t)(s * 16 + hf * 8 + j) * S + v0 + 2 * n);
      BE.u[j] = (u16)(xv & 0xFFFFu); BO.u[j] = (u16)(xv >> 16);
    }
    #pragma unroll
    for (int t = 0; t < 2; ++t) {
      accE[t] = MFMA32(A[t][s], BE.v, accE[t]);
      accO[t] = MFMA32(A[t][s], BO.v, accO[t]);
    }
  }
  #pragma unroll
  for (int t = 0; t < 2; ++t)
    #pragma unroll
    for (int r = 0; r < 16; ++r) {
      const int o = t * 32 + (r & 3) + 8 * (r >> 2) + 4 * hf;
      *(u32*)(xp + (size_t)o * S + v0 + 2 * n) = cvt_pk_bf16(accE[t][r], accO[t][r]);
    }
}

// ---- depthwise 3x3x3: LDS-staged planes, A/B tap-carry, dbuf, 1 barrier/step -
__device__ __forceinline__ void fma3(float* __restrict__ a,
    const float* __restrict__ r, float t0, float t1, float t2) {
  #pragma unroll
  for (int i = 0; i < 8; ++i) a[i] = fmaf(t0, r[i], a[i]);
  #pragma unroll
  for (int i = 0; i < 8; ++i) a[i] = fmaf(t1, r[i + 1], a[i]);
  #pragma unroll
  for (int i = 0; i < 8; ++i) a[i] = fmaf(t2, r[i + 2], a[i]);
}

// convA: c<32: t1[c] = SiLU(conv_ssm(xp[c])); c>=32: z_hi[c-32] = SiLU(conv_sym(xp[c]))
// convB: z_lo[c] = conv_mamba(t1[c])
// DCHUNKT must be even (2-round unroll keeps LDS buf ids static).
template<bool SILU, int DCHUNKT>
__global__ __launch_bounds__(192) void dwconv(const u16* __restrict__ srcA,
    const float* __restrict__ kwA, const float* __restrict__ bA,
    u16* __restrict__ dstA,
    const float* __restrict__ kwB, const float* __restrict__ bB,
    u16* __restrict__ dstB) {
  __shared__ u16 lds[2][LBUF];
  const int c = blockIdx.z;
  const u16* src = srcA + (size_t)c * S;
  u16* dst; const float* kwp; float bias;
  if (c < HALF) { dst = dstA + (size_t)c * S;          kwp = kwA + c * 27;          bias = bA[c]; }
  else          { dst = dstB + (size_t)(c - HALF) * S; kwp = kwB + (c - HALF) * 27; bias = bB[c - HALF]; }
  float kw[27];                            // wave-uniform
  #pragma unroll
  for (int i = 0; i < 27; ++i) kw[i] = kwp[i];

  const int tx = threadIdx.x, ty = threadIdx.y;    // 12 x 16
  const int tid = ty * 12 + tx;
  const int w8 = tx * 8;
  const int h0 = blockIdx.x * 16;
  const int d0 = blockIdx.y * DCHUNKT;

  // zero the pad chunks once (offsets 104*k, k=0..18, both buffers); never rewritten
  if (tid < 38) {
    const int b = tid / 19, k = tid % 19;
    *(u16x8*)&lds[b][RPAD * k] = zero8();
  }

  // staging assignment: chunk c0 = tid, chunk c1 = 192+tid (tid<24). 216 = 18x12.
  const int s_row0 = tid / 12, s_cc0 = tid % 12;
  const int s_row1 = (192 + tid) / 12, s_cc1 = (192 + tid) % 12;
  const bool has2 = tid < 24;
  const int s_h0 = h0 - 1 + s_row0;
  const int s_h1 = h0 - 1 + s_row1;
  const bool h0ok = (unsigned)s_h0 < DIM;
  const bool h1ok = has2 && ((unsigned)s_h1 < DIM);
  u16x8 vs0, vs1;

  #define STAGE_LOAD(DD) { \
    vs0 = zero8(); vs1 = zero8(); \
    if (((unsigned)(DD) < DIM) && h0ok) \
      vs0 = *(const u16x8*)(src + (size_t)(DD) * PLANE + s_h0 * DIM + s_cc0 * 8); \
    if (((unsigned)(DD) < DIM) && h1ok) \
      vs1 = *(const u16x8*)(src + (size_t)(DD) * PLANE + s_h1 * DIM + s_cc1 * 8); }

  #define STAGE_WRITE(WB) { \
    *(u16x8*)&lds[WB][8 + s_row0 * RPAD + s_cc0 * 8] = vs0; \
    if (has2) *(u16x8*)&lds[WB][8 + s_row1 * RPAD + s_cc1 * 8] = vs1; }

  float r0[10], r1[10], r2[10];
  float A[8], B[8], o8[8];

  // LDS window read: pads make w=-1 / w=96 / row-head all hit zero chunks.
  #define LOADROW(R, ROWI, RB) { \
    const u16* _lb = &lds[RB][8 + (ROWI) * RPAD + w8]; \
    const u16x8 _m = *(const u16x8*)_lb; \
    const u16 _lo = _lb[-1], _hi = _lb[8]; \
    R[0] = bf2f(_lo); \
    _Pragma("unroll") \
    for (int i = 0; i < 8; ++i) R[1 + i] = bf2f(_m[i]); \
    R[9] = bf2f(_hi); }

  #define LOADROWS(RB) { LOADROW(r0, ty, RB); LOADROW(r1, ty + 1, RB); LOADROW(r2, ty + 2, RB); }

  #define CBLK(ACC, K0) { \
    fma3(ACC, r0, kw[(K0) + 0], kw[(K0) + 1], kw[(K0) + 2]); \
    fma3(ACC, r1, kw[(K0) + 3], kw[(K0) + 4], kw[(K0) + 5]); \
    fma3(ACC, r2, kw[(K0) + 6], kw[(K0) + 7], kw[(K0) + 8]); }

  // ---- prologue ----
  STAGE_LOAD(d0 - 1);            // d0==0 -> zeros (bounds check)
  STAGE_WRITE(0);
  __syncthreads();

  LOADROWS(0);                   // plane d0-1
  STAGE_LOAD(d0);
  #pragma unroll
  for (int i = 0; i < 8; ++i) B[i] = bias;
  CBLK(B, 0);
  STAGE_WRITE(1);
  __syncthreads();

  LOADROWS(1);                   // plane d0
  STAGE_LOAD(d0 + 1);
  #pragma unroll
  for (int i = 0; i < 8; ++i) { A[i] = B[i]; B[i] = bias; }
  CBLK(A, 9);
  CBLK(B, 0);
  STAGE_WRITE(0);
  __syncthreads();

  // ---- main: round(d): read buf[(d-d0)&1], output d, stage plane d+2 ----
  u16* db = dst + (size_t)d0 * PLANE + (size_t)(h0 + ty) * DIM + w8;

  #define ROUND_BODY(D, RB, WB, DO_STG) { \
    LOADROWS(RB); \
    if (DO_STG) STAGE_LOAD((D) + 2); \
    _Pragma("unroll") \
    for (int i = 0; i < 8; ++i) o8[i] = A[i]; \
    CBLK(o8, 18); \
    _Pragma("unroll") \
    for (int i = 0; i < 8; ++i) A[i] = B[i]; \
    CBLK(A, 9); \
    _Pragma("unroll") \
    for (int i = 0; i < 8; ++i) B[i] = bias; \
    CBLK(B, 0); \
    if (SILU) { \
      _Pragma("unroll") \
      for (int i = 0; i < 8; ++i) o8[i] = silu(o8[i]); \
    } \
    union { u32 u[4]; u16x8 v; } _o; \
    _Pragma("unroll") \
    for (int i = 0; i < 4; ++i) _o.u[i] = cvt_pk_bf16(o8[2 * i], o8[2 * i + 1]); \
    *(u16x8*)db = _o.v; \
    db += PLANE; \
    if (DO_STG) STAGE_WRITE(WB); \
    __syncthreads(); }

  #pragma unroll 1
  for (int d = d0; d < d0 + DCHUNKT; d += 2) {
    ROUND_BODY(d, 0, 1, true);                                   // output d
    ROUND_BODY(d + 1, 1, 0, (d + 2) < d0 + DCHUNKT);             // output d+1
  }
  #undef ROUND_BODY
  #undef CBLK
  #undef LOADROWS
  #undef LOADROW
  #undef STAGE_WRITE
  #undef STAGE_LOAD
}

// --- K4b: 1x1 out_proj (32x32x16 MFMA) + bias + bf16 residual -> fp32 out -----
__global__ __launch_bounds__(256) void k4b_mfma(const u16* __restrict__ z_lo,
    const u16* __restrict__ z_hi, const u16* __restrict__ xb,
    const u16* __restrict__ Wo, const float* __restrict__ ob,
    float* __restrict__ out) {
  const int lane = threadIdx.x & 63, wid = threadIdx.x >> 6;
  const int n = lane & 31, hf = lane >> 5;
  const int v0 = blockIdx.x * 256 + wid * 64;
  bf16x8 A[2][4];
  #pragma unroll
  for (int t = 0; t < 2; ++t)
    #pragma unroll
    for (int s = 0; s < 4; ++s)
      A[t][s] = *(const bf16x8*)(Wo + (t * 32 + n) * C + s * 16 + hf * 8);

  f32x16 accE[2], accO[2];
  #pragma unroll
  for (int t = 0; t < 2; ++t)
    #pragma unroll
    for (int r = 0; r < 16; ++r) {
      const float b = ob[t * 32 + (r & 3) + 8 * (r >> 2) + 4 * hf];
      accE[t][r] = b; accO[t][r] = b;
    }

  #pragma unroll
  for (int s = 0; s < 4; ++s) {
    const u16* zbase = (s < 2) ? z_lo + (size_t)(s * 16) * S
                               : z_hi + (size_t)((s - 2) * 16) * S;
    union { u16 u[8]; bf16x8 v; } BE, BO;
    #pragma unroll
    for (int j = 0; j < 8; ++j) {
      const u32 zv = *(const u32*)(zbase + (size_t)(hf * 8 + j) * S + v0 + 2 * n);
      BE.u[j] = (u16)(zv & 0xFFFFu); BO.u[j] = (u16)(zv >> 16);
    }
    #pragma unroll
    for (int t = 0; t < 2; ++t) {
      accE[t] = MFMA32(A[t][s], BE.v, accE[t]);
      accO[t] = MFMA32(A[t][s], BO.v, accO[t]);
    }
  }
  #pragma unroll
  for (int t = 0; t < 2; ++t)
    #pragma unroll
    for (int r = 0; r < 16; ++r) {
      const int o = t * 32 + (r & 3) + 8 * (r >> 2) + 4 * hf;
      const u32 xr = *(const u32*)(xb + (size_t)o * S + v0 + 2 * n);
      float2 ov;
      ov.x = accE[t][r] + bf2f((u16)(xr & 0xFFFFu));
      ov.y = accO[t][r] + bf2f((u16)(xr >> 16));
      *(float2*)(out + (size_t)o * S + v0 + 2 * n) = ov;
    }
}

extern "C" void kernel_launch(void* const* d_in, const int* in_sizes, int n_in,
                              void* d_out, int out_size, void* d_ws, size_t ws_size,
                              hipStream_t stream) {
  const float* x      = (const float*)d_in[0];
  const float* norm_w = (const float*)d_in[1];
  const float* norm_b = (const float*)d_in[2];
  const float* in_w   = (const float*)d_in[3];
  const float* in_b   = (const float*)d_in[4];
  const float* ssm_w  = (const float*)d_in[5];
  const float* ssm_b  = (const float*)d_in[6];
  const float* mam_w  = (const float*)d_in[7];
  const float* mam_b  = (const float*)d_in[8];
  const float* sym_w  = (const float*)d_in[9];
  const float* sym_b  = (const float*)d_in[10];
  const float* out_w  = (const float*)d_in[11];
  const float* out_b  = (const float*)d_in[12];
  float* out = (float*)d_out;

  // Workspace (u16 units). z_lo ALIASES xp[0:32] (dead after convA; convB is
  // launched after convA completes, stream-ordered). Total ~340 MB.
  u16* xb   = (u16*)d_ws;                      // C*S bf16 copy of x (113.2 MB)
  u16* xp   = xb + (size_t)C * S;              // C*S bf16 (113.2 MB)
  u16* t1   = xp + (size_t)C * S;              // HALF*S bf16 (56.6 MB)
  u16* z_hi = t1 + (size_t)HALF * S;           // HALF*S bf16 (56.6 MB)
  u16* z_lo = xp;                              // alias, HALF*S
  float* psum  = (float*)(z_hi + (size_t)HALF * S);  // C*PARTS
  float* psq   = psum + C * PARTS;             // C*PARTS
  u16* Wp      = (u16*)(psq + C * PARTS);      // C*C bf16
  u16* Wo      = Wp + C * C;                   // C*C bf16
  float* biasp = (float*)(Wo + C * C);         // C fp32

  k1_stats<<<C * PARTS, 256, 0, stream>>>(x, xb, psum, psq);
  k1b_prep<<<1, 64, 0, stream>>>(psum, psq, norm_w, norm_b, in_w, in_b, out_w,
                                 Wp, biasp, Wo);
  k2_mfma<<<S / 256, 256, 0, stream>>>(xb, Wp, biasp, xp);
  // convA: ssm on xp[0:32] -> t1 ; sym on xp[32:64] -> z_hi (both SiLU); 24-chunks
  dwconv<true, 24><<<dim3(DIM / 16, 4, C), dim3(12, 16, 1), 0, stream>>>(
      xp, ssm_w, ssm_b, t1, sym_w, sym_b, z_hi);
  // convB: mamba on t1 -> z_lo (no activation); 12-chunks -> 2x blocks for TLP
  dwconv<false, 12><<<dim3(DIM / 16, 8, HALF), dim3(12, 16, 1), 0, stream>>>(
      t1, mam_w, mam_b, z_lo, mam_w, mam_b, z_lo);
  k4b_mfma<<<S / 256, 256, 0, stream>>>(z_lo, z_hi, xb, Wo, out_b, out);
}